// Round 1
// 144.161 us; speedup vs baseline: 1.0010x; 1.0010x over previous
//
#include <hip/hip_runtime.h>

#define NLEV 8
#define PTS_PER_BLOCK 32
#define ROW_F 51   // 3 + 6*NLEV

__global__ __launch_bounds__(256) void dagrid_kernel(
    const float* __restrict__ xyz,
    const float* __restrict__ data,
    const float* __restrict__ scales,
    const int*   __restrict__ level_offsets,
    const float* __restrict__ bounds,
    float* __restrict__ out,
    int npts)
{
    __shared__ float sxyz[PTS_PER_BLOCK * 3];
    __shared__ float sres[PTS_PER_BLOCK][ROW_F];

    const int tid = threadIdx.x;
    const int l   = tid & 7;        // level
    const int p   = tid >> 3;       // local point 0..31
    const int block_base = blockIdx.x * PTS_PER_BLOCK;

    // coalesced stage of 32 points' xyz
    if (tid < PTS_PER_BLOCK * 3) {
        int gi = block_base * 3 + tid;
        sxyz[tid] = (gi < npts * 3) ? xyz[gi] : 0.0f;
    }

    // per-level metadata: tiny divergent loads, issued before the barrier so
    // their latency hides under the sync
    const float scale = scales[l];
    const int   off_l = level_offsets[l];

    // bounds: (2,3) -> lo[3], hi_raw[3] (uniform -> scalar loads)
    const float lox = bounds[0], loy = bounds[1], loz = bounds[2];
    const float hix = bounds[3] - 1e-6f;
    const float hiy = bounds[4] - 1e-6f;
    const float hiz = bounds[5] - 1e-6f;
    const float size = fmaxf(fmaxf(bounds[3] - bounds[0], bounds[4] - bounds[1]),
                             bounds[5] - bounds[2]);
    const float inv_size = 1.0f / size;

    __syncthreads();

    const int n = block_base + p;
    const bool active = (n < npts);

    const float rx = sxyz[p * 3 + 0];
    const float ry = sxyz[p * 3 + 1];
    const float rz = sxyz[p * 3 + 2];

    float acc0 = 0.f, acc1 = 0.f, acc2 = 0.f, acc3 = 0.f, acc4 = 0.f, acc5 = 0.f;

    if (active) {
        const float x = fminf(fmaxf(rx, lox), hix);
        const float y = fminf(fmaxf(ry, loy), hiy);
        const float z = fminf(fmaxf(rz, loz), hiz);
        const float xn = (x - lox) * inv_size;
        const float yn = (y - loy) * inv_size;
        const float zn = (z - loz) * inv_size;

        const int r1   = (int)scale + 1;
        const int r1sq = r1 * r1;

        const float fx = xn * scale;
        const float fy = yn * scale;
        const float fz = zn * scale;
        const float bxf = floorf(fx), byf = floorf(fy), bzf = floorf(fz);
        const float ox = fx - bxf;
        const float oy = fy - byf;
        const float oz = fz - bzf;

        const int i000 = (int)bxf * r1sq + (int)byf * r1 + (int)bzf + off_l;

        const float* bp  = data + 3u * (unsigned)i000;
        const int    oy3 = 3 * r1;      // +y corner step (floats)
        const int    ox3 = 3 * r1sq;    // +x corner step (floats)

        // ---- GATHER PHASE: all 4 corner-pairs (24 floats, 8 VMEM instrs)
        // issued before any consumption, so the wave takes ONE miss round
        // instead of four dependent ones.
        float v[4][6];
        {
            const float* p0 = bp;
            const float* p1 = bp + oy3;
            const float* p2 = bp + ox3;
            const float* p3 = bp + ox3 + oy3;
            #pragma unroll
            for (int k = 0; k < 6; ++k) v[0][k] = p0[k];
            #pragma unroll
            for (int k = 0; k < 6; ++k) v[1][k] = p1[k];
            #pragma unroll
            for (int k = 0; k < 6; ++k) v[2][k] = p2[k];
            #pragma unroll
            for (int k = 0; k < 6; ++k) v[3][k] = p3[k];
        }

        // ---- COMPUTE PHASE
        const float freq = (float)(1 << l);
        const float wz0  = 1.0f - oz;
        const float wxc[2] = {1.0f - ox, ox};
        const float wyc[2] = {1.0f - oy, oy};

        #pragma unroll
        for (int s = 0; s < 4; ++s) {
            const float wxy = wxc[s >> 1] * wyc[s & 1];
            const float w0 = wxy * wz0;   // corner (cx,cy,0)
            const float w1 = wxy * oz;    // corner (cx,cy,1)
            float sn, cs;
            __sincosf(v[s][0] * freq, &sn, &cs); acc0 += w0 * sn; acc3 += w0 * cs;
            __sincosf(v[s][1] * freq, &sn, &cs); acc1 += w0 * sn; acc4 += w0 * cs;
            __sincosf(v[s][2] * freq, &sn, &cs); acc2 += w0 * sn; acc5 += w0 * cs;
            __sincosf(v[s][3] * freq, &sn, &cs); acc0 += w1 * sn; acc3 += w1 * cs;
            __sincosf(v[s][4] * freq, &sn, &cs); acc1 += w1 * sn; acc4 += w1 * cs;
            __sincosf(v[s][5] * freq, &sn, &cs); acc2 += w1 * sn; acc5 += w1 * cs;
        }
    }

    // stage results: row = [x, y, z, l0:6 feats, l1:6 feats, ...]
    {
        float* row = sres[p];
        const int c = 3 + l * 6;
        row[c + 0] = acc0; row[c + 1] = acc1; row[c + 2] = acc2;
        row[c + 3] = acc3; row[c + 4] = acc4; row[c + 5] = acc5;
        if (l == 0) { row[0] = rx; row[1] = ry; row[2] = rz; }
    }
    __syncthreads();

    // coalesced write: 32 * 51 = 1632 floats per block
    {
        const float* flat = &sres[0][0];
        float* ob = out + (size_t)block_base * ROW_F;
        const int lim = npts * ROW_F - block_base * ROW_F;
        for (int i = tid; i < PTS_PER_BLOCK * ROW_F; i += 256) {
            if (i < lim) ob[i] = flat[i];
        }
    }
}

extern "C" void kernel_launch(void* const* d_in, const int* in_sizes, int n_in,
                              void* d_out, int out_size, void* d_ws, size_t ws_size,
                              hipStream_t stream) {
    const float* xyz           = (const float*)d_in[0];
    const float* data          = (const float*)d_in[1];
    const float* scales        = (const float*)d_in[2];
    const int*   level_offsets = (const int*)d_in[3];
    const float* bounds        = (const float*)d_in[4];
    float* out = (float*)d_out;

    const int npts = in_sizes[0] / 3;
    const int nblocks = (npts + PTS_PER_BLOCK - 1) / PTS_PER_BLOCK;
    dagrid_kernel<<<nblocks, 256, 0, stream>>>(xyz, data, scales, level_offsets,
                                               bounds, out, npts);
}